// Round 14
// baseline (158.102 us; speedup 1.0000x reference)
//
#include <hip/hip_runtime.h>
#include <hip/hip_fp16.h>

#define HW_ (512 * 512)
#define NPIX (2048 * 512)
#define NBIN 4096           // 16x16x16 Morton bins
#define SORT_BLOCKS 256
#define PXPT 16             // pixels per thread in sort kernels

typedef _Float16 half_t;
typedef __attribute__((ext_vector_type(8))) _Float16 half8;
typedef __attribute__((ext_vector_type(2))) _Float16 half2v;
typedef __attribute__((ext_vector_type(4))) float f32x4;
typedef unsigned int uint;

__device__ __forceinline__ half8 splat8(float w)
{
    half_t h = (half_t)w;
    half8 r = {h, h, h, h, h, h, h, h};
    return r;
}

__device__ __forceinline__ uint packh(float lo, float hi)
{
    half_t l = (half_t)lo, h = (half_t)hi;
    unsigned short lb = __builtin_bit_cast(unsigned short, l);
    unsigned short hb = __builtin_bit_cast(unsigned short, h);
    return (uint)lb | ((uint)hb << 16);
}

__device__ __forceinline__ uint pkrtz_u32(float lo, float hi)
{
    return __builtin_bit_cast(uint, __builtin_amdgcn_cvt_pkrtz(lo, hi));
}

__device__ __forceinline__ float lky(float x) { return x >= 0.f ? x : 0.01f * x; }

// packed fp16 leaky: max(x, 0.01x) == leaky-relu
__device__ __forceinline__ uint pk_lky_u32(float a, float b)
{
    uint h = pkrtz_u32(a, b);
    half2v v = __builtin_bit_cast(half2v, h);
    half2v c = {(half_t)0.01f, (half_t)0.01f};
    half2v m = __builtin_elementwise_max(v, v * c);
    return __builtin_bit_cast(uint, m);
}

// ---------------------------------------------------------------------------
// Morton binning (16x16x16)
// ---------------------------------------------------------------------------
__device__ __forceinline__ unsigned spread4(int v)
{
    return (v & 1) | ((v & 2) << 2) | ((v & 4) << 4) | ((v & 8) << 6);
}

__device__ __forceinline__ unsigned bin_of(float cx, float cy, float cz)
{
    int qx = min(max((int)((cx + 1.f) * 8.f), 0), 15);
    int qy = min(max((int)((cy + 1.f) * 8.f), 0), 15);
    int qz = min(max((int)((cz + 1.f) * 8.f), 0), 15);
    return spread4(qx) | (spread4(qy) << 1) | (spread4(qz) << 2);
}

// ---------------------------------------------------------------------------
// big_k (merged): transpose planes (blocks 0..12287) || hist (next 256)
//                 || weight-fragment prep (last 10)
// ---------------------------------------------------------------------------
__global__ __launch_bounds__(256) void big_k(
    const float* __restrict__ xy, const float* __restrict__ xz,
    const float* __restrict__ yz, half_t* __restrict__ tp,
    const float* __restrict__ coords, unsigned* __restrict__ hist,
    const float* __restrict__ W0, const float* __restrict__ W1,
    const float* __restrict__ W2, const float* __restrict__ W3,
    const float* __restrict__ b0, const float* __restrict__ b1,
    const float* __restrict__ b2, const float* __restrict__ b3,
    uint* __restrict__ wfrag, float* __restrict__ bb)
{
    __shared__ __align__(16) uint sh[4096];   // 16 KB: tile or lcnt
    int b = blockIdx.x;
    int t = threadIdx.x;

    if (b < 12288) {
        // ---- transpose [C][H][W] fp32 -> [H][W][C] fp16 ----
        half_t (*tile)[68] = (half_t(*)[68])sh;
        int xc = b & 7;
        int y  = (b >> 3) & 511;
        int p  = b >> 12;
        const float* __restrict__ src = (p == 0) ? xy : (p == 1) ? xz : yz;
#pragma unroll
        for (int i = 0; i < 8; ++i) {
            int e  = i * 256 + t;
            int c  = e >> 6;
            int xl = e & 63;
            tile[c][xl] = (half_t)src[(size_t)c * HW_ + y * 512 + xc * 64 + xl];
        }
        __syncthreads();
        half_t* __restrict__ dst = tp + ((size_t)p * HW_ + y * 512 + xc * 64) * 32;
#pragma unroll
        for (int i = 0; i < 8; ++i) {
            int e  = i * 256 + t;
            int c  = e & 31;
            int xl = e >> 5;
            dst[(size_t)xl * 32 + c] = tile[c][xl];
        }
    } else if (b < 12288 + SORT_BLOCKS) {
        // ---- histogram (LDS-aggregated), overlapped with transpose ----
        uint* lcnt = sh;
#pragma unroll
        for (int i = 0; i < NBIN / 256; ++i) lcnt[i * 256 + t] = 0;
        __syncthreads();
        int base = (b - 12288) * (PXPT * 256);
#pragma unroll
        for (int i = 0; i < PXPT; ++i) {
            int px = base + i * 256 + t;
            float cx = coords[(size_t)px * 3 + 0];
            float cy = coords[(size_t)px * 3 + 1];
            float cz = coords[(size_t)px * 3 + 2];
            atomicAdd(&lcnt[bin_of(cx, cy, cz)], 1u);
        }
        __syncthreads();
#pragma unroll
        for (int i = 0; i < NBIN / 256; ++i) {
            uint v = lcnt[i * 256 + t];
            if (v) atomicAdd(&hist[i * 256 + t], v);
        }
    } else {
        // ---- weight prep: A = W^T fragments with folded k-permutation ----
        int tid = (b - 12288 - SORT_BLOCKS) * 256 + t;
        if (tid < 2304) {
            int f = tid >> 8, rem = tid & 255;
            int l = rem >> 2, u = rem & 3;     // lane l, uint u (elems 2u,2u+1)
            int jl = l & 15, g = l >> 4;
            float lo, hi;
            if (f < 4) {                        // L0: f = t_*2 + c
                int t_ = f >> 1, c = f & 1;
                int j  = t_ * 16 + jl;
                int k0 = 32 * c + 8 * g + 2 * u;
                float sc = c ? 1.f : (1.f / 3.f);
                lo = W0[k0 * 32 + j] * sc;
                hi = W0[(k0 + 1) * 32 + j] * sc;
            } else if (f < 8) {                 // L1 (4,5), L2 (6,7)
                const float* W = (f < 6) ? W1 : W2;
                int t_ = f & 1;
                int j  = t_ * 16 + jl;
                int klo = (u < 2) ? (4 * g + 2 * u) : (16 + 4 * g + 2 * u - 4);
                lo = W[klo * 32 + j];
                hi = W[(klo + 1) * 32 + j];
            } else {                            // L3 (outputs padded to 16)
                int klo = (u < 2) ? (4 * g + 2 * u) : (16 + 4 * g + 2 * u - 4);
                lo = (jl < 4) ? W3[klo * 4 + jl] : 0.f;
                hi = (jl < 4) ? W3[(klo + 1) * 4 + jl] : 0.f;
            }
            wfrag[tid] = packh(lo, hi);
        } else if (tid < 2304 + 112) {
            int u = tid - 2304;
            float v;
            if (u < 32)      v = b0[u];
            else if (u < 64) v = b1[u - 32];
            else if (u < 96) v = b2[u - 64];
            else             v = (u - 96 < 4) ? b3[u - 96] : 0.f;
            bb[u] = v;
        }
    }
}

// ---------------------------------------------------------------------------
// scatter (with integrated per-block scan of hist)
// ---------------------------------------------------------------------------
__global__ __launch_bounds__(256) void scatter_k(const float* __restrict__ coords,
                                                 const unsigned* __restrict__ hist,
                                                 unsigned* __restrict__ resv,
                                                 float4* __restrict__ sorted)
{
    __shared__ unsigned pref[NBIN];
    __shared__ unsigned lcnt[NBIN];
    __shared__ unsigned lbase[NBIN];
    __shared__ unsigned part[256];
    int t = threadIdx.x;

    unsigned loc[16], s = 0;
#pragma unroll
    for (int i = 0; i < 16; ++i) { loc[i] = s; s += hist[t * 16 + i]; }
    part[t] = s;
#pragma unroll
    for (int i = 0; i < NBIN / 256; ++i) lcnt[i * 256 + t] = 0;
    __syncthreads();
    for (int d = 1; d < 256; d <<= 1) {
        unsigned v = (t >= d) ? part[t - d] : 0u;
        __syncthreads();
        part[t] += v;
        __syncthreads();
    }
    unsigned base0 = (t == 0) ? 0u : part[t - 1];
#pragma unroll
    for (int i = 0; i < 16; ++i) pref[t * 16 + i] = base0 + loc[i];
    __syncthreads();

    int base = blockIdx.x * (PXPT * 256);
    float cxv[PXPT], cyv[PXPT], czv[PXPT];
    uint sav[PXPT];
#pragma unroll
    for (int i = 0; i < PXPT; ++i) {
        int px = base + i * 256 + t;
        cxv[i] = coords[(size_t)px * 3 + 0];
        cyv[i] = coords[(size_t)px * 3 + 1];
        czv[i] = coords[(size_t)px * 3 + 2];
        unsigned bn = bin_of(cxv[i], cyv[i], czv[i]);
        unsigned r  = atomicAdd(&lcnt[bn], 1u);
        sav[i] = (bn << 16) | r;
    }
    __syncthreads();
#pragma unroll
    for (int i = 0; i < NBIN / 256; ++i) {
        int bin = i * 256 + t;
        uint v = lcnt[bin];
        lbase[bin] = v ? (pref[bin] + atomicAdd(&resv[bin], v)) : 0u;
    }
    __syncthreads();

#pragma unroll
    for (int i = 0; i < PXPT; ++i) {
        int px = base + i * 256 + t;
        unsigned bn = sav[i] >> 16, r = sav[i] & 0xffffu;
        sorted[lbase[bn] + r] = make_float4(cxv[i], cyv[i], czv[i],
                                            __uint_as_float((uint)px));
    }
}

// ---------------------------------------------------------------------------
// Bilinear helpers
// ---------------------------------------------------------------------------
__device__ __forceinline__ void axis1d(float gc, int& i0, int& i1, float& tf)
{
    float ic = fmaf(gc, 255.5f, 255.5f);   // (gc+1)*0.5*511
    float fc = floorf(ic);
    tf = ic - fc;
    int c0 = (int)fc;
    i0 = min(max(c0, 0), 511);
    i1 = min(max(c0 + 1, 0), 511);
}

// quad-cooperative interp: lane loads chunk ch (16B) of all 4 corners;
// the quad (4 consecutive lanes, same corner addresses base) covers the
// full 64B corner -> one cache-line request per corner. [R13 lesson:
// coalescing merges LANE-CONTIGUOUS runs; keep quads on one corner.]
__device__ __forceinline__ void interp_q(const half_t* __restrict__ pl,
                                         int i00, int i01, int i10, int i11,
                                         float tc, float tr, int ch, half8& acc)
{
    const half_t* __restrict__ p = pl + ch * 8;
    half8 a = *(const half8*)(p + (size_t)i00 * 32);
    half8 b = *(const half8*)(p + (size_t)i01 * 32);
    half8 c = *(const half8*)(p + (size_t)i10 * 32);
    half8 d = *(const half8*)(p + (size_t)i11 * 32);
    float w00 = (1.f - tc) * (1.f - tr);
    float w01 = tc * (1.f - tr);
    float w10 = (1.f - tc) * tr;
    float w11 = tc * tr;
    acc = acc + a * splat8(w00) + b * splat8(w01) + c * splat8(w10) + d * splat8(w11);
}

__device__ __forceinline__ void corners(float gx, float gy,
                                        int& i00, int& i01, int& i10, int& i11,
                                        float& wnw, float& wne, float& wsw, float& wse)
{
    int x0, x1, y0, y1; float tx, ty;
    axis1d(gx, x0, x1, tx);
    axis1d(gy, y0, y1, ty);
    i00 = y0 * 512 + x0;
    i01 = y0 * 512 + x1;
    i10 = y1 * 512 + x0;
    i11 = y1 * 512 + x1;
    wnw = (1.f - tx) * (1.f - ty);
    wne = tx * (1.f - ty);
    wsw = (1.f - tx) * ty;
    wse = tx * ty;
}

// quad-cooperative gather pass q: lane handles pixel q*16+(l>>2), chunk l&3.
__device__ __forceinline__ half8 gather_pass(const half_t* __restrict__ tp,
                                             float cx, float cy, float cz,
                                             int q, int pq, int ch)
{
    int pp = q * 16 + pq;
    float gx = __shfl(cx, pp);
    float gy = __shfl(cy, pp);
    float gz = __shfl(cz, pp);
    int x0, x1, y0, y1, z0, z1;
    float tx, ty, tz;
    axis1d(gx, x0, x1, tx);
    axis1d(gy, y0, y1, ty);
    axis1d(gz, z0, z1, tz);
    half8 acc = {};
    interp_q(tp,
             y0 * 512 + x0, y0 * 512 + x1, y1 * 512 + x0, y1 * 512 + x1,
             tx, ty, ch, acc);
    interp_q(tp + (size_t)HW_ * 32,
             z0 * 512 + x0, z0 * 512 + x1, z1 * 512 + x0, z1 * 512 + x1,
             tx, tz, ch, acc);
    interp_q(tp + (size_t)2 * HW_ * 32,
             z0 * 512 + y0, z0 * 512 + y1, z1 * 512 + y0, z1 * 512 + y1,
             ty, tz, ch, acc);
    return acc;
}

// one 16-pixel tile's full MLP: Ba via lane-crossbar of the gather pass,
// Bb (posenc) computed directly in B-fragment layout, biases from LDS.
__device__ __forceinline__ void mlp_tile(
    int pt, half8 accv, float cx, float cy, float cz, uint idreg,
    const half8* __restrict__ wf, const float* __restrict__ sbb,
    const float* __restrict__ gauss, int l, int jl, int g,
    float* __restrict__ out)
{
    const float TWO_PI = 6.283185307179586f;

    // Ba: lane (jl,g) <- gather lane 4*jl+g (pixel pt*16+jl, chunk g)
    uint4 av = __builtin_bit_cast(uint4, accv);
    int srcl = 4 * jl + g;
    uint4 bu;
    bu.x = (uint)__shfl((int)av.x, srcl);
    bu.y = (uint)__shfl((int)av.y, srcl);
    bu.z = (uint)__shfl((int)av.z, srcl);
    bu.w = (uint)__shfl((int)av.w, srcl);
    half8 Ba = __builtin_bit_cast(half8, bu);

    // Bb: posenc chunk g for pixel p = pt*16+jl (g<2: sin, else cos)
    int p = pt * 16 + jl;
    float sx = __shfl(cx, p) * TWO_PI;
    float sy = __shfl(cy, p) * TWO_PI;
    float sz = __shfl(cz, p) * TWO_PI;
    const int c0 = 8 * (g & 1);
    half8 Bb;
#pragma unroll
    for (int i = 0; i < 8; ++i) {
        float pr = sx * gauss[c0 + i] + sy * gauss[16 + c0 + i]
                 + sz * gauss[32 + c0 + i];
        float v = (g < 2) ? __sinf(pr) : __cosf(pr);
        Bb[i] = (half_t)v;
    }

    // L0: 64 -> 32
    f32x4 d0 = *(const f32x4*)(sbb +  0 + g * 4);
    f32x4 d1 = *(const f32x4*)(sbb + 16 + g * 4);
    d0 = __builtin_amdgcn_mfma_f32_16x16x32_f16(wf[0], Ba, d0, 0, 0, 0);
    d0 = __builtin_amdgcn_mfma_f32_16x16x32_f16(wf[1], Bb, d0, 0, 0, 0);
    d1 = __builtin_amdgcn_mfma_f32_16x16x32_f16(wf[2], Ba, d1, 0, 0, 0);
    d1 = __builtin_amdgcn_mfma_f32_16x16x32_f16(wf[3], Bb, d1, 0, 0, 0);
    uint4 u1;
    u1.x = pk_lky_u32(d0[0], d0[1]);
    u1.y = pk_lky_u32(d0[2], d0[3]);
    u1.z = pk_lky_u32(d1[0], d1[1]);
    u1.w = pk_lky_u32(d1[2], d1[3]);
    half8 B1 = __builtin_bit_cast(half8, u1);

    // L1
    d0 = *(const f32x4*)(sbb + 32 + g * 4);
    d1 = *(const f32x4*)(sbb + 48 + g * 4);
    d0 = __builtin_amdgcn_mfma_f32_16x16x32_f16(wf[4], B1, d0, 0, 0, 0);
    d1 = __builtin_amdgcn_mfma_f32_16x16x32_f16(wf[5], B1, d1, 0, 0, 0);
    uint4 u2;
    u2.x = pk_lky_u32(d0[0], d0[1]);
    u2.y = pk_lky_u32(d0[2], d0[3]);
    u2.z = pk_lky_u32(d1[0], d1[1]);
    u2.w = pk_lky_u32(d1[2], d1[3]);
    half8 B2 = __builtin_bit_cast(half8, u2);

    // L2
    d0 = *(const f32x4*)(sbb + 64 + g * 4);
    d1 = *(const f32x4*)(sbb + 80 + g * 4);
    d0 = __builtin_amdgcn_mfma_f32_16x16x32_f16(wf[6], B2, d0, 0, 0, 0);
    d1 = __builtin_amdgcn_mfma_f32_16x16x32_f16(wf[7], B2, d1, 0, 0, 0);
    uint4 u3;
    u3.x = pk_lky_u32(d0[0], d0[1]);
    u3.y = pk_lky_u32(d0[2], d0[3]);
    u3.z = pk_lky_u32(d1[0], d1[1]);
    u3.w = pk_lky_u32(d1[2], d1[3]);
    half8 B3 = __builtin_bit_cast(half8, u3);

    // L3: 32 -> 4 (outputs on lanes 0..15)
    f32x4 d3 = *(const f32x4*)(sbb + 96 + g * 4);
    d3 = __builtin_amdgcn_mfma_f32_16x16x32_f16(wf[8], B3, d3, 0, 0, 0);
    int gid = __shfl((int)idreg, pt * 16 + (l & 15));
    if (l < 16) {
        *(f32x4*)(out + (size_t)(uint)gid * 4) = d3;
    }
}

// ---------------------------------------------------------------------------
// Fused decoder: register-resident, all 4 gather passes issued up-front
// (max memory-level parallelism), then 4 MLP tiles consume.
// ---------------------------------------------------------------------------
__global__ __launch_bounds__(128) void decoder_fused_k(
    const half_t* __restrict__ tp, const float4* __restrict__ sorted,
    const float* __restrict__ gauss, const uint* __restrict__ wfrag,
    const float* __restrict__ bb, float* __restrict__ out)
{
    __shared__ __align__(16) float sbb[112];
    const int t  = threadIdx.x;
    if (t < 112) sbb[t] = bb[t];
    __syncthreads();

    const int l  = t & 63;
    const int wv = t >> 6;
    const int jl = l & 15, g = l >> 4;
    const int ch = l & 3;        // gather: chunk index
    const int pq = l >> 2;       // gather: pixel-in-pass (0..15)

    int b   = blockIdx.x;                      // 8192 blocks
    int swz = (b & 7) * 1024 + (b >> 3);       // XCD-chunked Morton ranges
    int j   = (swz * 2 + wv) * 64 + l;

    float4 s = sorted[j];
    uint idreg = __float_as_uint(s.w);
    float cx = s.x, cy = s.y, cz = s.z;

    // weight fragments (9 x 4 VGPRs)
    half8 wf[9];
#pragma unroll
    for (int f = 0; f < 9; ++f) {
        uint4 u = *(const uint4*)(wfrag + f * 256 + l * 4);
        wf[f] = __builtin_bit_cast(half8, u);
    }

    // all four gather passes issued before any MLP tile
    half8 a0 = gather_pass(tp, cx, cy, cz, 0, pq, ch);
    half8 a1 = gather_pass(tp, cx, cy, cz, 1, pq, ch);
    half8 a2 = gather_pass(tp, cx, cy, cz, 2, pq, ch);
    half8 a3 = gather_pass(tp, cx, cy, cz, 3, pq, ch);
    mlp_tile(0, a0, cx, cy, cz, idreg, wf, sbb, gauss, l, jl, g, out);
    mlp_tile(1, a1, cx, cy, cz, idreg, wf, sbb, gauss, l, jl, g, out);
    mlp_tile(2, a2, cx, cy, cz, idreg, wf, sbb, gauss, l, jl, g, out);
    mlp_tile(3, a3, cx, cy, cz, idreg, wf, sbb, gauss, l, jl, g, out);
}

// ---------------------------------------------------------------------------
// Fallback scalar decoder (tiny workspace) — correctness path only
// ---------------------------------------------------------------------------
__device__ __forceinline__ void sample_dir(const float* __restrict__ pl,
                                           float gx, float gy, float* __restrict__ acc)
{
    int i00, i01, i10, i11;
    float wnw, wne, wsw, wse;
    corners(gx, gy, i00, i01, i10, i11, wnw, wne, wsw, wse);
#pragma unroll
    for (int c = 0; c < 32; ++c) {
        const float* __restrict__ bq = pl + (size_t)c * HW_;
        acc[c] += wnw * bq[i00] + wne * bq[i01] + wsw * bq[i10] + wse * bq[i11];
    }
}

__global__ __launch_bounds__(256) void decoder_fb_k(
    const float* __restrict__ xy, const float* __restrict__ xz,
    const float* __restrict__ yz,
    const float* __restrict__ coords, const float* __restrict__ gauss,
    const float* __restrict__ W0, const float* __restrict__ b0,
    const float* __restrict__ W1, const float* __restrict__ b1,
    const float* __restrict__ W2, const float* __restrict__ b2,
    const float* __restrict__ W3, const float* __restrict__ b3,
    float* __restrict__ out)
{
    int pix = blockIdx.x * 256 + threadIdx.x;
    float cx = coords[(size_t)pix * 3 + 0];
    float cy = coords[(size_t)pix * 3 + 1];
    float cz = coords[(size_t)pix * 3 + 2];

    float act[64];
#pragma unroll
    for (int i = 0; i < 32; ++i) act[i] = 0.f;
    sample_dir(xy, cx, cy, act);
    sample_dir(xz, cx, cz, act);
    sample_dir(yz, cy, cz, act);
#pragma unroll
    for (int i = 0; i < 32; ++i) act[i] *= (1.f / 3.f);

    const float TWO_PI = 6.283185307179586f;
    float px = cx * TWO_PI, py = cy * TWO_PI, pz = cz * TWO_PI;
#pragma unroll
    for (int c = 0; c < 16; ++c) {
        float pr = px * gauss[c] + py * gauss[16 + c] + pz * gauss[32 + c];
        act[32 + c] = __sinf(pr);
        act[48 + c] = __cosf(pr);
    }

    float h[32];
#pragma unroll
    for (int jj = 0; jj < 32; ++jj) h[jj] = b0[jj];
#pragma unroll
    for (int k = 0; k < 64; ++k) {
        float a = act[k];
#pragma unroll
        for (int jj = 0; jj < 32; ++jj) h[jj] = fmaf(a, W0[k * 32 + jj], h[jj]);
    }
#pragma unroll
    for (int jj = 0; jj < 32; ++jj) act[jj] = lky(h[jj]);
#pragma unroll
    for (int jj = 0; jj < 32; ++jj) h[jj] = b1[jj];
#pragma unroll
    for (int k = 0; k < 32; ++k) {
        float a = act[k];
#pragma unroll
        for (int jj = 0; jj < 32; ++jj) h[jj] = fmaf(a, W1[k * 32 + jj], h[jj]);
    }
#pragma unroll
    for (int jj = 0; jj < 32; ++jj) act[jj] = lky(h[jj]);
#pragma unroll
    for (int jj = 0; jj < 32; ++jj) h[jj] = b2[jj];
#pragma unroll
    for (int k = 0; k < 32; ++k) {
        float a = act[k];
#pragma unroll
        for (int jj = 0; jj < 32; ++jj) h[jj] = fmaf(a, W2[k * 32 + jj], h[jj]);
    }
#pragma unroll
    for (int jj = 0; jj < 32; ++jj) act[jj] = lky(h[jj]);
    float o[4];
#pragma unroll
    for (int jj = 0; jj < 4; ++jj) o[jj] = b3[jj];
#pragma unroll
    for (int k = 0; k < 32; ++k) {
        float a = act[k];
#pragma unroll
        for (int jj = 0; jj < 4; ++jj) o[jj] = fmaf(a, W3[k * 4 + jj], o[jj]);
    }
    *(float4*)(out + (size_t)pix * 4) = make_float4(o[0], o[1], o[2], o[3]);
}

// ---------------------------------------------------------------------------
extern "C" void kernel_launch(void* const* d_in, const int* in_sizes, int n_in,
                              void* d_out, int out_size, void* d_ws, size_t ws_size,
                              hipStream_t stream)
{
    const float* xy     = (const float*)d_in[0];
    const float* xz     = (const float*)d_in[1];
    const float* yz     = (const float*)d_in[2];
    const float* coords = (const float*)d_in[3];
    const float* gauss  = (const float*)d_in[4];
    const float* W0     = (const float*)d_in[5];
    const float* b0     = (const float*)d_in[6];
    const float* W1     = (const float*)d_in[7];
    const float* b1     = (const float*)d_in[8];
    const float* W2     = (const float*)d_in[9];
    const float* b2     = (const float*)d_in[10];
    const float* W3     = (const float*)d_in[11];
    const float* b3     = (const float*)d_in[12];
    float* out = (float*)d_out;

    const size_t plane_bytes = (size_t)3 * HW_ * 32 * sizeof(half_t);   // 48 MB
    const size_t hist_off    = plane_bytes;
    const size_t resv_off    = hist_off + NBIN * 4;
    const size_t wfrag_off   = resv_off + NBIN * 4;
    const size_t bb_off      = wfrag_off + 12288;
    const size_t sorted_off  = bb_off + 4096;
    const size_t need_fused  = sorted_off + (size_t)NPIX * sizeof(float4);

    if (ws_size >= need_fused) {
        half_t*   tp     = (half_t*)d_ws;
        unsigned* hist   = (unsigned*)((char*)d_ws + hist_off);
        unsigned* resv   = (unsigned*)((char*)d_ws + resv_off);
        uint*     wfrag  = (uint*)((char*)d_ws + wfrag_off);
        float*    bb     = (float*)((char*)d_ws + bb_off);
        float4*   sorted = (float4*)((char*)d_ws + sorted_off);

        (void)hipMemsetAsync(hist, 0, 2 * NBIN * 4, stream);   // hist + resv
        big_k<<<12288 + SORT_BLOCKS + 10, 256, 0, stream>>>(
            xy, xz, yz, tp, coords, hist,
            W0, W1, W2, W3, b0, b1, b2, b3, wfrag, bb);
        scatter_k<<<SORT_BLOCKS, 256, 0, stream>>>(coords, hist, resv, sorted);
        decoder_fused_k<<<NPIX / 128, 128, 0, stream>>>(
            tp, sorted, gauss, wfrag, bb, out);
    } else {
        decoder_fb_k<<<NPIX / 256, 256, 0, stream>>>(
            xy, xz, yz, coords, gauss,
            W0, b0, W1, b1, W2, b2, W3, b3, out);
    }
}

// Round 15
// 134.604 us; speedup vs baseline: 1.1746x; 1.1746x over previous
//
#include <hip/hip_runtime.h>
#include <hip/hip_fp16.h>

#define HW_ (512 * 512)
#define NPIX (2048 * 512)
#define NBIN 4096           // 16x16x16 Morton bins
#define SORT_BLOCKS 256
#define PXPT 16             // pixels per thread in sort kernels

typedef _Float16 half_t;
typedef __attribute__((ext_vector_type(8))) _Float16 half8;
typedef __attribute__((ext_vector_type(2))) _Float16 half2v;
typedef __attribute__((ext_vector_type(4))) float f32x4;
typedef unsigned int uint;

__device__ __forceinline__ half8 splat8(float w)
{
    half_t h = (half_t)w;
    half8 r = {h, h, h, h, h, h, h, h};
    return r;
}

__device__ __forceinline__ uint packh(float lo, float hi)
{
    half_t l = (half_t)lo, h = (half_t)hi;
    unsigned short lb = __builtin_bit_cast(unsigned short, l);
    unsigned short hb = __builtin_bit_cast(unsigned short, h);
    return (uint)lb | ((uint)hb << 16);
}

__device__ __forceinline__ uint pkrtz_u32(float lo, float hi)
{
    return __builtin_bit_cast(uint, __builtin_amdgcn_cvt_pkrtz(lo, hi));
}

__device__ __forceinline__ float lky(float x) { return x >= 0.f ? x : 0.01f * x; }

// packed fp16 leaky: max(x, 0.01x) == leaky-relu
__device__ __forceinline__ uint pk_lky_u32(float a, float b)
{
    uint h = pkrtz_u32(a, b);
    half2v v = __builtin_bit_cast(half2v, h);
    half2v c = {(half_t)0.01f, (half_t)0.01f};
    half2v m = __builtin_elementwise_max(v, v * c);
    return __builtin_bit_cast(uint, m);
}

// ---------------------------------------------------------------------------
// Morton binning (16x16x16)
// ---------------------------------------------------------------------------
__device__ __forceinline__ unsigned spread4(int v)
{
    return (v & 1) | ((v & 2) << 2) | ((v & 4) << 4) | ((v & 8) << 6);
}

__device__ __forceinline__ unsigned bin_of(float cx, float cy, float cz)
{
    int qx = min(max((int)((cx + 1.f) * 8.f), 0), 15);
    int qy = min(max((int)((cy + 1.f) * 8.f), 0), 15);
    int qz = min(max((int)((cz + 1.f) * 8.f), 0), 15);
    return spread4(qx) | (spread4(qy) << 1) | (spread4(qz) << 2);
}

// ---------------------------------------------------------------------------
// big_k (merged): transpose planes (blocks 0..12287) || hist (next 256)
//                 || weight-fragment prep (last 10)
// ---------------------------------------------------------------------------
__global__ __launch_bounds__(256) void big_k(
    const float* __restrict__ xy, const float* __restrict__ xz,
    const float* __restrict__ yz, half_t* __restrict__ tp,
    const float* __restrict__ coords, unsigned* __restrict__ hist,
    const float* __restrict__ W0, const float* __restrict__ W1,
    const float* __restrict__ W2, const float* __restrict__ W3,
    const float* __restrict__ b0, const float* __restrict__ b1,
    const float* __restrict__ b2, const float* __restrict__ b3,
    uint* __restrict__ wfrag, float* __restrict__ bb)
{
    __shared__ __align__(16) uint sh[4096];   // 16 KB: tile or lcnt
    int b = blockIdx.x;
    int t = threadIdx.x;

    if (b < 12288) {
        // ---- transpose [C][H][W] fp32 -> [H][W][C] fp16 ----
        half_t (*tile)[68] = (half_t(*)[68])sh;
        int xc = b & 7;
        int y  = (b >> 3) & 511;
        int p  = b >> 12;
        const float* __restrict__ src = (p == 0) ? xy : (p == 1) ? xz : yz;
#pragma unroll
        for (int i = 0; i < 8; ++i) {
            int e  = i * 256 + t;
            int c  = e >> 6;
            int xl = e & 63;
            tile[c][xl] = (half_t)src[(size_t)c * HW_ + y * 512 + xc * 64 + xl];
        }
        __syncthreads();
        half_t* __restrict__ dst = tp + ((size_t)p * HW_ + y * 512 + xc * 64) * 32;
#pragma unroll
        for (int i = 0; i < 8; ++i) {
            int e  = i * 256 + t;
            int c  = e & 31;
            int xl = e >> 5;
            dst[(size_t)xl * 32 + c] = tile[c][xl];
        }
    } else if (b < 12288 + SORT_BLOCKS) {
        // ---- histogram (LDS-aggregated), overlapped with transpose ----
        uint* lcnt = sh;
#pragma unroll
        for (int i = 0; i < NBIN / 256; ++i) lcnt[i * 256 + t] = 0;
        __syncthreads();
        int base = (b - 12288) * (PXPT * 256);
#pragma unroll
        for (int i = 0; i < PXPT; ++i) {
            int px = base + i * 256 + t;
            float cx = coords[(size_t)px * 3 + 0];
            float cy = coords[(size_t)px * 3 + 1];
            float cz = coords[(size_t)px * 3 + 2];
            atomicAdd(&lcnt[bin_of(cx, cy, cz)], 1u);
        }
        __syncthreads();
#pragma unroll
        for (int i = 0; i < NBIN / 256; ++i) {
            uint v = lcnt[i * 256 + t];
            if (v) atomicAdd(&hist[i * 256 + t], v);
        }
    } else {
        // ---- weight prep: A = W^T fragments with folded k-permutation ----
        int tid = (b - 12288 - SORT_BLOCKS) * 256 + t;
        if (tid < 2304) {
            int f = tid >> 8, rem = tid & 255;
            int l = rem >> 2, u = rem & 3;     // lane l, uint u (elems 2u,2u+1)
            int jl = l & 15, g = l >> 4;
            float lo, hi;
            if (f < 4) {                        // L0: f = t_*2 + c
                int t_ = f >> 1, c = f & 1;
                int j  = t_ * 16 + jl;
                int k0 = 32 * c + 8 * g + 2 * u;
                float sc = c ? 1.f : (1.f / 3.f);
                lo = W0[k0 * 32 + j] * sc;
                hi = W0[(k0 + 1) * 32 + j] * sc;
            } else if (f < 8) {                 // L1 (4,5), L2 (6,7)
                const float* W = (f < 6) ? W1 : W2;
                int t_ = f & 1;
                int j  = t_ * 16 + jl;
                int klo = (u < 2) ? (4 * g + 2 * u) : (16 + 4 * g + 2 * u - 4);
                lo = W[klo * 32 + j];
                hi = W[(klo + 1) * 32 + j];
            } else {                            // L3 (outputs padded to 16)
                int klo = (u < 2) ? (4 * g + 2 * u) : (16 + 4 * g + 2 * u - 4);
                lo = (jl < 4) ? W3[klo * 4 + jl] : 0.f;
                hi = (jl < 4) ? W3[(klo + 1) * 4 + jl] : 0.f;
            }
            wfrag[tid] = packh(lo, hi);
        } else if (tid < 2304 + 112) {
            int u = tid - 2304;
            float v;
            if (u < 32)      v = b0[u];
            else if (u < 64) v = b1[u - 32];
            else if (u < 96) v = b2[u - 64];
            else             v = (u - 96 < 4) ? b3[u - 96] : 0.f;
            bb[u] = v;
        }
    }
}

// ---------------------------------------------------------------------------
// scatter (with integrated per-block scan of hist)
// ---------------------------------------------------------------------------
__global__ __launch_bounds__(256) void scatter_k(const float* __restrict__ coords,
                                                 const unsigned* __restrict__ hist,
                                                 unsigned* __restrict__ resv,
                                                 float4* __restrict__ sorted)
{
    __shared__ unsigned pref[NBIN];
    __shared__ unsigned lcnt[NBIN];
    __shared__ unsigned lbase[NBIN];
    __shared__ unsigned part[256];
    int t = threadIdx.x;

    unsigned loc[16], s = 0;
#pragma unroll
    for (int i = 0; i < 16; ++i) { loc[i] = s; s += hist[t * 16 + i]; }
    part[t] = s;
#pragma unroll
    for (int i = 0; i < NBIN / 256; ++i) lcnt[i * 256 + t] = 0;
    __syncthreads();
    for (int d = 1; d < 256; d <<= 1) {
        unsigned v = (t >= d) ? part[t - d] : 0u;
        __syncthreads();
        part[t] += v;
        __syncthreads();
    }
    unsigned base0 = (t == 0) ? 0u : part[t - 1];
#pragma unroll
    for (int i = 0; i < 16; ++i) pref[t * 16 + i] = base0 + loc[i];
    __syncthreads();

    int base = blockIdx.x * (PXPT * 256);
    float cxv[PXPT], cyv[PXPT], czv[PXPT];
    uint sav[PXPT];
#pragma unroll
    for (int i = 0; i < PXPT; ++i) {
        int px = base + i * 256 + t;
        cxv[i] = coords[(size_t)px * 3 + 0];
        cyv[i] = coords[(size_t)px * 3 + 1];
        czv[i] = coords[(size_t)px * 3 + 2];
        unsigned bn = bin_of(cxv[i], cyv[i], czv[i]);
        unsigned r  = atomicAdd(&lcnt[bn], 1u);
        sav[i] = (bn << 16) | r;
    }
    __syncthreads();
#pragma unroll
    for (int i = 0; i < NBIN / 256; ++i) {
        int bin = i * 256 + t;
        uint v = lcnt[bin];
        lbase[bin] = v ? (pref[bin] + atomicAdd(&resv[bin], v)) : 0u;
    }
    __syncthreads();

#pragma unroll
    for (int i = 0; i < PXPT; ++i) {
        int px = base + i * 256 + t;
        unsigned bn = sav[i] >> 16, r = sav[i] & 0xffffu;
        sorted[lbase[bn] + r] = make_float4(cxv[i], cyv[i], czv[i],
                                            __uint_as_float((uint)px));
    }
}

// ---------------------------------------------------------------------------
// Bilinear helpers
// ---------------------------------------------------------------------------
__device__ __forceinline__ void axis1d(float gc, int& i0, int& i1, float& tf)
{
    float ic = fmaf(gc, 255.5f, 255.5f);   // (gc+1)*0.5*511
    float fc = floorf(ic);
    tf = ic - fc;
    int c0 = (int)fc;
    i0 = min(max(c0, 0), 511);
    i1 = min(max(c0 + 1, 0), 511);
}

// quad-cooperative interp: lane loads chunk ch (16B) of all 4 corners;
// 4 consecutive lanes (one quad) cover the full 64B corner -> one
// cache-line request per corner (lane-contiguous runs merge; R13 lesson).
__device__ __forceinline__ void interp_q(const half_t* __restrict__ pl,
                                         int i00, int i01, int i10, int i11,
                                         float tc, float tr, int ch, half8& acc)
{
    const half_t* __restrict__ p = pl + ch * 8;
    half8 a = *(const half8*)(p + (size_t)i00 * 32);
    half8 b = *(const half8*)(p + (size_t)i01 * 32);
    half8 c = *(const half8*)(p + (size_t)i10 * 32);
    half8 d = *(const half8*)(p + (size_t)i11 * 32);
    float w00 = (1.f - tc) * (1.f - tr);
    float w01 = tc * (1.f - tr);
    float w10 = (1.f - tc) * tr;
    float w11 = tc * tr;
    acc = acc + a * splat8(w00) + b * splat8(w01) + c * splat8(w10) + d * splat8(w11);
}

__device__ __forceinline__ void corners(float gx, float gy,
                                        int& i00, int& i01, int& i10, int& i11,
                                        float& wnw, float& wne, float& wsw, float& wse)
{
    int x0, x1, y0, y1; float tx, ty;
    axis1d(gx, x0, x1, tx);
    axis1d(gy, y0, y1, ty);
    i00 = y0 * 512 + x0;
    i01 = y0 * 512 + x1;
    i10 = y1 * 512 + x0;
    i11 = y1 * 512 + x1;
    wnw = (1.f - tx) * (1.f - ty);
    wne = tx * (1.f - ty);
    wsw = (1.f - tx) * ty;
    wse = tx * ty;
}

// quad-cooperative gather pass q: lane handles pixel q*16+(l>>2), chunk l&3.
__device__ __forceinline__ half8 gather_pass(const half_t* __restrict__ tp,
                                             float cx, float cy, float cz,
                                             int q, int pq, int ch)
{
    int pp = q * 16 + pq;
    float gx = __shfl(cx, pp);
    float gy = __shfl(cy, pp);
    float gz = __shfl(cz, pp);
    int x0, x1, y0, y1, z0, z1;
    float tx, ty, tz;
    axis1d(gx, x0, x1, tx);
    axis1d(gy, y0, y1, ty);
    axis1d(gz, z0, z1, tz);
    half8 acc = {};
    interp_q(tp,
             y0 * 512 + x0, y0 * 512 + x1, y1 * 512 + x0, y1 * 512 + x1,
             tx, ty, ch, acc);
    interp_q(tp + (size_t)HW_ * 32,
             z0 * 512 + x0, z0 * 512 + x1, z1 * 512 + x0, z1 * 512 + x1,
             tx, tz, ch, acc);
    interp_q(tp + (size_t)2 * HW_ * 32,
             z0 * 512 + y0, z0 * 512 + y1, z1 * 512 + y0, z1 * 512 + y1,
             ty, tz, ch, acc);
    return acc;
}

// one 16-pixel tile's full MLP: Ba via lane-crossbar of the gather pass,
// Bb (posenc) computed directly in B-fragment layout, biases from LDS.
__device__ __forceinline__ void mlp_tile(
    int pt, half8 accv, float cx, float cy, float cz, uint idreg,
    const half8* __restrict__ wf, const float* __restrict__ sbb,
    const float* __restrict__ gauss, int l, int jl, int g,
    float* __restrict__ out)
{
    const float TWO_PI = 6.283185307179586f;

    // Ba: lane (jl,g) <- gather lane 4*jl+g (pixel pt*16+jl, chunk g)
    uint4 av = __builtin_bit_cast(uint4, accv);
    int srcl = 4 * jl + g;
    uint4 bu;
    bu.x = (uint)__shfl((int)av.x, srcl);
    bu.y = (uint)__shfl((int)av.y, srcl);
    bu.z = (uint)__shfl((int)av.z, srcl);
    bu.w = (uint)__shfl((int)av.w, srcl);
    half8 Ba = __builtin_bit_cast(half8, bu);

    // Bb: posenc chunk g for pixel p = pt*16+jl (g<2: sin, else cos)
    int p = pt * 16 + jl;
    float sx = __shfl(cx, p) * TWO_PI;
    float sy = __shfl(cy, p) * TWO_PI;
    float sz = __shfl(cz, p) * TWO_PI;
    const int c0 = 8 * (g & 1);
    half8 Bb;
#pragma unroll
    for (int i = 0; i < 8; ++i) {
        float pr = sx * gauss[c0 + i] + sy * gauss[16 + c0 + i]
                 + sz * gauss[32 + c0 + i];
        float v = (g < 2) ? __sinf(pr) : __cosf(pr);
        Bb[i] = (half_t)v;
    }

    // L0: 64 -> 32
    f32x4 d0 = *(const f32x4*)(sbb +  0 + g * 4);
    f32x4 d1 = *(const f32x4*)(sbb + 16 + g * 4);
    d0 = __builtin_amdgcn_mfma_f32_16x16x32_f16(wf[0], Ba, d0, 0, 0, 0);
    d0 = __builtin_amdgcn_mfma_f32_16x16x32_f16(wf[1], Bb, d0, 0, 0, 0);
    d1 = __builtin_amdgcn_mfma_f32_16x16x32_f16(wf[2], Ba, d1, 0, 0, 0);
    d1 = __builtin_amdgcn_mfma_f32_16x16x32_f16(wf[3], Bb, d1, 0, 0, 0);
    uint4 u1;
    u1.x = pk_lky_u32(d0[0], d0[1]);
    u1.y = pk_lky_u32(d0[2], d0[3]);
    u1.z = pk_lky_u32(d1[0], d1[1]);
    u1.w = pk_lky_u32(d1[2], d1[3]);
    half8 B1 = __builtin_bit_cast(half8, u1);

    // L1
    d0 = *(const f32x4*)(sbb + 32 + g * 4);
    d1 = *(const f32x4*)(sbb + 48 + g * 4);
    d0 = __builtin_amdgcn_mfma_f32_16x16x32_f16(wf[4], B1, d0, 0, 0, 0);
    d1 = __builtin_amdgcn_mfma_f32_16x16x32_f16(wf[5], B1, d1, 0, 0, 0);
    uint4 u2;
    u2.x = pk_lky_u32(d0[0], d0[1]);
    u2.y = pk_lky_u32(d0[2], d0[3]);
    u2.z = pk_lky_u32(d1[0], d1[1]);
    u2.w = pk_lky_u32(d1[2], d1[3]);
    half8 B2 = __builtin_bit_cast(half8, u2);

    // L2
    d0 = *(const f32x4*)(sbb + 64 + g * 4);
    d1 = *(const f32x4*)(sbb + 80 + g * 4);
    d0 = __builtin_amdgcn_mfma_f32_16x16x32_f16(wf[6], B2, d0, 0, 0, 0);
    d1 = __builtin_amdgcn_mfma_f32_16x16x32_f16(wf[7], B2, d1, 0, 0, 0);
    uint4 u3;
    u3.x = pk_lky_u32(d0[0], d0[1]);
    u3.y = pk_lky_u32(d0[2], d0[3]);
    u3.z = pk_lky_u32(d1[0], d1[1]);
    u3.w = pk_lky_u32(d1[2], d1[3]);
    half8 B3 = __builtin_bit_cast(half8, u3);

    // L3: 32 -> 4 (outputs on lanes 0..15)
    f32x4 d3 = *(const f32x4*)(sbb + 96 + g * 4);
    d3 = __builtin_amdgcn_mfma_f32_16x16x32_f16(wf[8], B3, d3, 0, 0, 0);
    int gid = __shfl((int)idreg, pt * 16 + (l & 15));
    if (l < 16) {
        *(f32x4*)(out + (size_t)(uint)gid * 4) = d3;
    }
}

// ---------------------------------------------------------------------------
// Fused decoder: register-resident, ONE gather pass in flight ahead of the
// MLP (R12's best balance: VGPR ~92, ~4 waves/SIMD; 4-deep spilled to 148).
// ---------------------------------------------------------------------------
__global__ __launch_bounds__(128) void decoder_fused_k(
    const half_t* __restrict__ tp, const float4* __restrict__ sorted,
    const float* __restrict__ gauss, const uint* __restrict__ wfrag,
    const float* __restrict__ bb, float* __restrict__ out)
{
    __shared__ __align__(16) float sbb[112];
    const int t  = threadIdx.x;
    if (t < 112) sbb[t] = bb[t];
    __syncthreads();

    const int l  = t & 63;
    const int wv = t >> 6;
    const int jl = l & 15, g = l >> 4;
    const int ch = l & 3;        // gather: chunk index
    const int pq = l >> 2;       // gather: pixel-in-pass (0..15)

    int b   = blockIdx.x;                      // 8192 blocks
    int swz = (b & 7) * 1024 + (b >> 3);       // XCD-chunked Morton ranges
    int j   = (swz * 2 + wv) * 64 + l;

    float4 s = sorted[j];
    uint idreg = __float_as_uint(s.w);
    float cx = s.x, cy = s.y, cz = s.z;

    // weight fragments (9 x 4 VGPRs)
    half8 wf[9];
#pragma unroll
    for (int f = 0; f < 9; ++f) {
        uint4 u = *(const uint4*)(wfrag + f * 256 + l * 4);
        wf[f] = __builtin_bit_cast(half8, u);
    }

    // software pipeline: one gather pass in flight ahead of the MLP
    half8 a0 = gather_pass(tp, cx, cy, cz, 0, pq, ch);
    half8 a1 = gather_pass(tp, cx, cy, cz, 1, pq, ch);
    mlp_tile(0, a0, cx, cy, cz, idreg, wf, sbb, gauss, l, jl, g, out);
    half8 a2 = gather_pass(tp, cx, cy, cz, 2, pq, ch);
    mlp_tile(1, a1, cx, cy, cz, idreg, wf, sbb, gauss, l, jl, g, out);
    half8 a3 = gather_pass(tp, cx, cy, cz, 3, pq, ch);
    mlp_tile(2, a2, cx, cy, cz, idreg, wf, sbb, gauss, l, jl, g, out);
    mlp_tile(3, a3, cx, cy, cz, idreg, wf, sbb, gauss, l, jl, g, out);
}

// ---------------------------------------------------------------------------
// Fallback scalar decoder (tiny workspace) — correctness path only
// ---------------------------------------------------------------------------
__device__ __forceinline__ void sample_dir(const float* __restrict__ pl,
                                           float gx, float gy, float* __restrict__ acc)
{
    int i00, i01, i10, i11;
    float wnw, wne, wsw, wse;
    corners(gx, gy, i00, i01, i10, i11, wnw, wne, wsw, wse);
#pragma unroll
    for (int c = 0; c < 32; ++c) {
        const float* __restrict__ bq = pl + (size_t)c * HW_;
        acc[c] += wnw * bq[i00] + wne * bq[i01] + wsw * bq[i10] + wse * bq[i11];
    }
}

__global__ __launch_bounds__(256) void decoder_fb_k(
    const float* __restrict__ xy, const float* __restrict__ xz,
    const float* __restrict__ yz,
    const float* __restrict__ coords, const float* __restrict__ gauss,
    const float* __restrict__ W0, const float* __restrict__ b0,
    const float* __restrict__ W1, const float* __restrict__ b1,
    const float* __restrict__ W2, const float* __restrict__ b2,
    const float* __restrict__ W3, const float* __restrict__ b3,
    float* __restrict__ out)
{
    int pix = blockIdx.x * 256 + threadIdx.x;
    float cx = coords[(size_t)pix * 3 + 0];
    float cy = coords[(size_t)pix * 3 + 1];
    float cz = coords[(size_t)pix * 3 + 2];

    float act[64];
#pragma unroll
    for (int i = 0; i < 32; ++i) act[i] = 0.f;
    sample_dir(xy, cx, cy, act);
    sample_dir(xz, cx, cz, act);
    sample_dir(yz, cy, cz, act);
#pragma unroll
    for (int i = 0; i < 32; ++i) act[i] *= (1.f / 3.f);

    const float TWO_PI = 6.283185307179586f;
    float px = cx * TWO_PI, py = cy * TWO_PI, pz = cz * TWO_PI;
#pragma unroll
    for (int c = 0; c < 16; ++c) {
        float pr = px * gauss[c] + py * gauss[16 + c] + pz * gauss[32 + c];
        act[32 + c] = __sinf(pr);
        act[48 + c] = __cosf(pr);
    }

    float h[32];
#pragma unroll
    for (int jj = 0; jj < 32; ++jj) h[jj] = b0[jj];
#pragma unroll
    for (int k = 0; k < 64; ++k) {
        float a = act[k];
#pragma unroll
        for (int jj = 0; jj < 32; ++jj) h[jj] = fmaf(a, W0[k * 32 + jj], h[jj]);
    }
#pragma unroll
    for (int jj = 0; jj < 32; ++jj) act[jj] = lky(h[jj]);
#pragma unroll
    for (int jj = 0; jj < 32; ++jj) h[jj] = b1[jj];
#pragma unroll
    for (int k = 0; k < 32; ++k) {
        float a = act[k];
#pragma unroll
        for (int jj = 0; jj < 32; ++jj) h[jj] = fmaf(a, W1[k * 32 + jj], h[jj]);
    }
#pragma unroll
    for (int jj = 0; jj < 32; ++jj) act[jj] = lky(h[jj]);
#pragma unroll
    for (int jj = 0; jj < 32; ++jj) h[jj] = b2[jj];
#pragma unroll
    for (int k = 0; k < 32; ++k) {
        float a = act[k];
#pragma unroll
        for (int jj = 0; jj < 32; ++jj) h[jj] = fmaf(a, W2[k * 32 + jj], h[jj]);
    }
#pragma unroll
    for (int jj = 0; jj < 32; ++jj) act[jj] = lky(h[jj]);
    float o[4];
#pragma unroll
    for (int jj = 0; jj < 4; ++jj) o[jj] = b3[jj];
#pragma unroll
    for (int k = 0; k < 32; ++k) {
        float a = act[k];
#pragma unroll
        for (int jj = 0; jj < 4; ++jj) o[jj] = fmaf(a, W3[k * 4 + jj], o[jj]);
    }
    *(float4*)(out + (size_t)pix * 4) = make_float4(o[0], o[1], o[2], o[3]);
}

// ---------------------------------------------------------------------------
extern "C" void kernel_launch(void* const* d_in, const int* in_sizes, int n_in,
                              void* d_out, int out_size, void* d_ws, size_t ws_size,
                              hipStream_t stream)
{
    const float* xy     = (const float*)d_in[0];
    const float* xz     = (const float*)d_in[1];
    const float* yz     = (const float*)d_in[2];
    const float* coords = (const float*)d_in[3];
    const float* gauss  = (const float*)d_in[4];
    const float* W0     = (const float*)d_in[5];
    const float* b0     = (const float*)d_in[6];
    const float* W1     = (const float*)d_in[7];
    const float* b1     = (const float*)d_in[8];
    const float* W2     = (const float*)d_in[9];
    const float* b2     = (const float*)d_in[10];
    const float* W3     = (const float*)d_in[11];
    const float* b3     = (const float*)d_in[12];
    float* out = (float*)d_out;

    const size_t plane_bytes = (size_t)3 * HW_ * 32 * sizeof(half_t);   // 48 MB
    const size_t hist_off    = plane_bytes;
    const size_t resv_off    = hist_off + NBIN * 4;
    const size_t wfrag_off   = resv_off + NBIN * 4;
    const size_t bb_off      = wfrag_off + 12288;
    const size_t sorted_off  = bb_off + 4096;
    const size_t need_fused  = sorted_off + (size_t)NPIX * sizeof(float4);

    if (ws_size >= need_fused) {
        half_t*   tp     = (half_t*)d_ws;
        unsigned* hist   = (unsigned*)((char*)d_ws + hist_off);
        unsigned* resv   = (unsigned*)((char*)d_ws + resv_off);
        uint*     wfrag  = (uint*)((char*)d_ws + wfrag_off);
        float*    bb     = (float*)((char*)d_ws + bb_off);
        float4*   sorted = (float4*)((char*)d_ws + sorted_off);

        (void)hipMemsetAsync(hist, 0, 2 * NBIN * 4, stream);   // hist + resv
        big_k<<<12288 + SORT_BLOCKS + 10, 256, 0, stream>>>(
            xy, xz, yz, tp, coords, hist,
            W0, W1, W2, W3, b0, b1, b2, b3, wfrag, bb);
        scatter_k<<<SORT_BLOCKS, 256, 0, stream>>>(coords, hist, resv, sorted);
        decoder_fused_k<<<NPIX / 128, 128, 0, stream>>>(
            tp, sorted, gauss, wfrag, bb, out);
    } else {
        decoder_fb_k<<<NPIX / 256, 256, 0, stream>>>(
            xy, xz, yz, coords, gauss,
            W0, b0, W1, b1, W2, b2, W3, b3, out);
    }
}